// Round 9
// baseline (536.048 us; speedup 1.0000x reference)
//
#include <hip/hip_runtime.h>

// AdaptiveGraphConvolution on MI355X (gfx950)
// out = sum_l m_l * (A_l @ x) @ W_l + bias
//
// R9: kill the bucket-scatter write storm (R8 fill: 212MB WRITE_SIZE for a
// 16MB payload -- partial-line writebacks from a 12.8MB shared scatter
// region). fill2 scatters only within its block-private 32KB chunk window
// (lines fully covered by one CU); sort2 PULLS runs from the chunk windows
// (scattered reads, no write-allocate) and writes final CSR coalesced.
// Gather = R8's L2-sliced + decoupled-load structure. ~44.25 MB workspace.

constexpr int N = 50000;
constexpr int E = 800000;
constexpr int D = 128;
constexpr int L = 4;
constexpr int BSH = 4;            // 16 rows per bucket
constexpr int NB = N >> BSH;      // 3125 buckets
constexpr int NCHK = 100;
constexpr int CHUNK = E / NCHK;   // 8000
constexpr int CAP = 1024;         // max bucket size in sort2 (mean 256)

__device__ inline unsigned bf16rne(unsigned u) {
    return (u + 0x7FFFu + ((u >> 16) & 1u)) >> 16;
}

// ---------------------------------------------------------------------------
// 0) x -> 4 feature-sliced bf16 tables: xb[q][row][fl] packs features
//    (32q+2fl, 32q+2fl+1).
// ---------------------------------------------------------------------------
__global__ __launch_bounds__(256) void cvt_x_kernel(
    const float* __restrict__ x, unsigned* __restrict__ xb)
{
    int i = blockIdx.x * 256 + threadIdx.x;     // 0 .. N*64
    int row = i >> 6, j = i & 63;
    int q = j >> 4, fl = j & 15;
    float2 v = *reinterpret_cast<const float2*>(x + (size_t)row * D + q * 32 + fl * 2);
    xb[((size_t)q * N + row) * 16 + fl] =
        bf16rne(__float_as_uint(v.x)) | (bf16rne(__float_as_uint(v.y)) << 16);
}

// ---------------------------------------------------------------------------
// 1) fill2 (hist + chunk-local sort), grid (NCHK, L):
//    LDS hist over 3125 buckets -> pcnt counts (u16) -> LDS exclusive
//    prefix -> chunkoff (u16) -> rank-scatter sidxT = e | rl<<28 into the
//    block's PRIVATE 32KB window (full line coverage, no write-allocate waste).
// ---------------------------------------------------------------------------
__global__ __launch_bounds__(256) void fill2_kernel(
    const int* __restrict__ edge_rows,
    unsigned short* __restrict__ pcnt,       // [L][NCHK][NB] counts out
    unsigned short* __restrict__ chunkoff,   // [L][NCHK][NB] local offsets out
    unsigned* __restrict__ sidxT)            // [L][E] chunk-local sorted
{
    __shared__ int cnt[NB];
    __shared__ int psum[256];
    const int blk = blockIdx.x, g = blockIdx.y, tid = threadIdx.x;

    for (int i = tid; i < NB; i += 256) cnt[i] = 0;
    __syncthreads();

    const int* rows = edge_rows + (size_t)g * E + (size_t)blk * CHUNK;
    for (int i = tid; i < CHUNK; i += 256)
        atomicAdd(&cnt[rows[i] >> BSH], 1);
    __syncthreads();

    unsigned short* pc = pcnt + ((size_t)g * NCHK + blk) * NB;
    for (int i = tid; i < NB; i += 256) pc[i] = (unsigned short)cnt[i];
    __syncthreads();

    // exclusive prefix over the 3125 bins (13 bins/thread + block scan)
    constexpr int CB = (NB + 255) / 256;   // 13
    const int base = tid * CB;
    int s = 0;
#pragma unroll
    for (int j = 0; j < CB; ++j) {
        int idx = base + j;
        if (idx < NB) s += cnt[idx];
    }
    psum[tid] = s;
    __syncthreads();
    for (int off = 1; off < 256; off <<= 1) {
        int v = (tid >= off) ? psum[tid - off] : 0;
        __syncthreads();
        psum[tid] += v;
        __syncthreads();
    }
    int carry = (tid == 0) ? 0 : psum[tid - 1];
#pragma unroll
    for (int j = 0; j < CB; ++j) {
        int idx = base + j;
        if (idx < NB) {
            int c = cnt[idx];
            cnt[idx] = carry;
            carry += c;
        }
    }
    __syncthreads();

    unsigned short* co = chunkoff + ((size_t)g * NCHK + blk) * NB;
    for (int i = tid; i < NB; i += 256) co[i] = (unsigned short)cnt[i];
    __syncthreads();

    // rank-scatter into the private window (rows re-read: L1/L2-hot)
    unsigned* st = sidxT + (size_t)g * E + (size_t)blk * CHUNK;
    for (int i = tid; i < CHUNK; i += 256) {
        int r = rows[i];
        int b = r >> BSH;
        int pos = atomicAdd(&cnt[b], 1);
        st[pos] = (unsigned)(blk * CHUNK + i) | ((unsigned)(r & 15) << 28);
    }
}

// ---------------------------------------------------------------------------
// 2a) Column pass: pcnt counts -> within-bucket cross-chunk offsets;
//     bucket totals -> bstart.
// ---------------------------------------------------------------------------
__global__ __launch_bounds__(256) void scan1_kernel(
    unsigned short* __restrict__ pcnt, int* __restrict__ bstart)
{
    const int b = blockIdx.x * 256 + threadIdx.x;
    const int g = blockIdx.y;
    if (b >= NB) return;
    unsigned run = 0;
    unsigned short* p = pcnt + (size_t)g * NCHK * NB + b;
    for (int blk = 0; blk < NCHK; ++blk) {
        unsigned v = p[(size_t)blk * NB];
        p[(size_t)blk * NB] = (unsigned short)run;
        run += v;
    }
    bstart[(size_t)g * (NB + 1) + b] = (int)run;
}

// ---------------------------------------------------------------------------
// 2b) Per-graph exclusive scan of bucket totals.
// ---------------------------------------------------------------------------
__global__ __launch_bounds__(1024) void scan2_kernel(int* __restrict__ bstart)
{
    __shared__ int sums[1024];
    int* bs = bstart + (size_t)blockIdx.x * (NB + 1);
    const int t = threadIdx.x;
    int tv[4];
    int s = 0;
#pragma unroll
    for (int i = 0; i < 4; ++i) {
        int idx = t * 4 + i;
        tv[i] = (idx < NB) ? bs[idx] : 0;
        s += tv[i];
    }
    sums[t] = s;
    __syncthreads();
    for (int off = 1; off < 1024; off <<= 1) {
        int v = (t >= off) ? sums[t - off] : 0;
        __syncthreads();
        sums[t] += v;
        __syncthreads();
    }
    int ex = (t == 0) ? 0 : sums[t - 1];
#pragma unroll
    for (int i = 0; i < 4; ++i) {
        int idx = t * 4 + i;
        if (idx < NB) { bs[idx] = ex; ex += tv[i]; }
    }
    if (t == 0) bs[NB] = E;
}

// ---------------------------------------------------------------------------
// 3) sort2 (pull), grid (NB, L): threads 0..99 copy their chunk's run from
//    sidxT into LDS at the canonical within-bucket position; 16-bin counting
//    sort by rl; fetch col/val (random reads, L2/L3-resident); write final
//    cv COALESCED + CSR rowptr.
// ---------------------------------------------------------------------------
__global__ __launch_bounds__(256) void sort2_kernel(
    const unsigned* __restrict__ sidxT,          // [L][E]
    const unsigned short* __restrict__ pcnt,     // [L][NCHK][NB] offsets
    const unsigned short* __restrict__ chunkoff, // [L][NCHK][NB]
    const int* __restrict__ bstart,              // [L][NB+1]
    const int* __restrict__ edge_cols,           // [L][E]
    const float* __restrict__ edge_vals,         // [L][E]
    unsigned* __restrict__ cv,                   // [L][E] final
    int* __restrict__ rowptr)                    // [L][N+1]
{
    __shared__ unsigned su[CAP], ss[CAP];
    __shared__ int rc[17], rcur[16];
    const int b = blockIdx.x, g = blockIdx.y, tid = threadIdx.x;
    const int beg = bstart[(size_t)g * (NB + 1) + b];
    const int tot = bstart[(size_t)g * (NB + 1) + b + 1] - beg;
    const int cnt = tot < CAP ? tot : CAP;
    int* rp = rowptr + (size_t)g * (N + 1);
    if (b == 0 && tid == 0) rp[N] = E;
    if (tid < 17) rc[tid] = 0;

    // pull phase: thread c copies chunk c's run
    if (tid < NCHK) {
        const int c = tid;
        const size_t pbase = ((size_t)g * NCHK + c) * NB + b;
        int off = pcnt[pbase];
        int nxt = (c == NCHK - 1) ? tot : (int)pcnt[pbase + NB];
        int len = nxt - off;
        const unsigned* st = sidxT + (size_t)g * E + (size_t)c * CHUNK + chunkoff[pbase];
        for (int i = 0; i < len; ++i) {
            int p = off + i;
            if (p < CAP) su[p] = st[i];
        }
    }
    __syncthreads();

    for (int i = tid; i < cnt; i += 256) atomicAdd(&rc[(su[i] >> 28) + 1], 1);
    __syncthreads();
    if (tid == 0) {
        int run = 0;
#pragma unroll
        for (int r = 1; r <= 16; ++r) { run += rc[r]; rc[r] = run; }
    }
    __syncthreads();
    if (tid < 16) {
        rcur[tid] = rc[tid];
        rp[b * 16 + tid] = beg + rc[tid];
    }
    __syncthreads();
    for (int i = tid; i < cnt; i += 256) {
        unsigned v = su[i];
        int p = atomicAdd(&rcur[v >> 28], 1);
        ss[p] = v;
    }
    __syncthreads();

    const int* cols_g = edge_cols + (size_t)g * E;
    const float* vals_g = edge_vals + (size_t)g * E;
    unsigned* cvg = cv + (size_t)g * E;
    for (int i = tid; i < cnt; i += 256) {
        int e = (int)(ss[i] & 0x0FFFFFFFu);
        cvg[beg + i] = (unsigned)cols_g[e] |
                       (bf16rne(__float_as_uint(vals_g[e])) << 16);
    }
}

// ---------------------------------------------------------------------------
// 4) Sliced gather, pass q, grid (N/4, L) -- R8 structure (L2-resident
//    3.2MB slice + batch-preload + shfl broadcast, branch-free padding).
// ---------------------------------------------------------------------------
__global__ __launch_bounds__(256) void gather_kernel(
    const unsigned* __restrict__ xb,      // [4][N][16]
    const unsigned* __restrict__ cv,      // [L][E]
    const int* __restrict__ rowptr,       // [L][N+1]
    unsigned* __restrict__ y,             // [L][N][16]
    int q)
{
    const int tid = threadIdx.x;
    const int row = blockIdx.x * 4 + (tid >> 6);
    const int l = blockIdx.y;
    const int lane = tid & 63;
    const int sub = lane >> 4, fl = lane & 15;

    const unsigned* xq = xb + (size_t)q * N * 16;
    const unsigned* cvg = cv + (size_t)l * E;
    const int* rp = rowptr + (size_t)l * (N + 1);

    const int beg = rp[row], end = rp[row + 1];
    float accx = 0.f, accy = 0.f;
    for (int base = beg; base < end; base += 64) {
        int cnt = end - base;
        if (cnt > 64) cnt = 64;
        unsigned cvr = (lane < cnt) ? cvg[base + lane] : 0u;
        const int nk = (cnt + 3) >> 2;
#pragma unroll 4
        for (int k = 0; k < nk; ++k) {
            unsigned c = __shfl(cvr, k * 4 + sub);
            float v = __uint_as_float(c & 0xFFFF0000u);   // padding -> +0.0
            unsigned col = c & 0xFFFFu;
            unsigned xv = xq[(size_t)col * 16 + fl];
            accx = fmaf(v, __uint_as_float(xv << 16), accx);
            accy = fmaf(v, __uint_as_float(xv & 0xFFFF0000u), accy);
        }
    }
    accx += __shfl_xor(accx, 16); accx += __shfl_xor(accx, 32);
    accy += __shfl_xor(accy, 16); accy += __shfl_xor(accy, 32);
    if (lane < 16)
        y[((size_t)l * N + row) * 16 + fl] =
            bf16rne(__float_as_uint(accx)) | (bf16rne(__float_as_uint(accy)) << 16);
}

// ---------------------------------------------------------------------------
// 5) K=32 GEMM-accumulate, pass q:
//    out[n][f] (+)= sum_l sum_{d in slice q} y_l[n][d] * (m_l W_l[d][f])
// ---------------------------------------------------------------------------
__global__ __launch_bounds__(256) void gemm_kernel(
    const unsigned* __restrict__ y,      // [L][N][16]
    const float* __restrict__ W,         // [L][D][D]
    const float* __restrict__ mix,
    const float* __restrict__ bias,
    float* __restrict__ out,
    int q)
{
    __shared__ float lw[32][D];   // 16 KB
    __shared__ float ly[32][32];  // 4 KB

    const int tid = threadIdx.x;
    const int lane = tid & 63, wave = tid >> 6;
    const int r0 = blockIdx.x * 32;
    const int f0 = 2 * lane;
    const int wr = wave * 8;

    float2 acc[8];
#pragma unroll
    for (int r = 0; r < 8; ++r) {
        int row = r0 + wr + r;
        if (q == 0) {
            acc[r].x = bias[f0];
            acc[r].y = bias[f0 + 1];
        } else if (row < N) {
            acc[r] = *reinterpret_cast<const float2*>(out + (size_t)row * D + f0);
        } else {
            acc[r] = make_float2(0.f, 0.f);
        }
    }

    for (int l = 0; l < L; ++l) {
        const float m = mix[l];
        {   // stage W slice [32][128] * m
            const float4* ws = reinterpret_cast<const float4*>(
                W + (size_t)l * D * D + (size_t)q * 32 * D);
#pragma unroll
            for (int i = 0; i < 4; ++i) {
                int idx = i * 256 + tid;
                float4 w = ws[idx];
                reinterpret_cast<float4*>(lw)[idx] =
                    make_float4(m * w.x, m * w.y, m * w.z, m * w.w);
            }
        }
        {   // stage y tile [32][32] f32 from packed bf16
            int rl = tid >> 3, j2 = tid & 7;
            int row = r0 + rl;
            uint2 p = make_uint2(0u, 0u);
            if (row < N)
                p = *reinterpret_cast<const uint2*>(
                    y + ((size_t)l * N + row) * 16 + j2 * 2);
            float* dst = &ly[rl][j2 * 4];
            dst[0] = __uint_as_float(p.x << 16);
            dst[1] = __uint_as_float(p.x & 0xFFFF0000u);
            dst[2] = __uint_as_float(p.y << 16);
            dst[3] = __uint_as_float(p.y & 0xFFFF0000u);
        }
        __syncthreads();
#pragma unroll
        for (int d = 0; d < 32; ++d) {
            float2 wv = *reinterpret_cast<const float2*>(&lw[d][f0]);
#pragma unroll
            for (int r = 0; r < 8; ++r) {
                float ys = ly[wr + r][d];
                acc[r].x = fmaf(ys, wv.x, acc[r].x);
                acc[r].y = fmaf(ys, wv.y, acc[r].y);
            }
        }
        __syncthreads();
    }

#pragma unroll
    for (int r = 0; r < 8; ++r) {
        int row = r0 + wr + r;
        if (row < N)
            *reinterpret_cast<float2*>(out + (size_t)row * D + f0) = acc[r];
    }
}

extern "C" void kernel_launch(void* const* d_in, const int* in_sizes, int n_in,
                              void* d_out, int out_size, void* d_ws, size_t ws_size,
                              hipStream_t stream)
{
    const float* x         = (const float*)d_in[0];
    const int*   edge_rows = (const int*)d_in[1];
    const int*   edge_cols = (const int*)d_in[2];
    const float* edge_vals = (const float*)d_in[3];
    const float* W         = (const float*)d_in[4];
    const float* mix       = (const float*)d_in[5];
    const float* bias      = (const float*)d_in[6];
    float* out = (float*)d_out;

    // Workspace (~44.25 MB):
    // sidxT [L][E] u32 (12.8M, reused as y after sort2) | pcnt u16 (2.5M) |
    // chunkoff u16 (2.5M) | bstart | rowptr | cv [L][E] u32 (12.8M) |
    // xb [4][N][16] u32 (12.8M)
    unsigned*       sidxT    = (unsigned*)d_ws;
    unsigned short* pcnt     = (unsigned short*)(sidxT + (size_t)L * E);
    unsigned short* chunkoff = pcnt + (size_t)L * NCHK * NB;
    int*            bstart   = (int*)(chunkoff + (size_t)L * NCHK * NB);
    int*            rowptr   = bstart + (size_t)L * (NB + 1);
    unsigned*       cv       = (unsigned*)(rowptr + (size_t)L * (N + 1));
    unsigned*       xb       = cv + (size_t)L * E;
    unsigned*       y        = sidxT;   // alias: sidxT dead after sort2

    cvt_x_kernel<<<(N * 64) / 256, 256, 0, stream>>>(x, xb);
    fill2_kernel<<<dim3(NCHK, L), 256, 0, stream>>>(edge_rows, pcnt, chunkoff, sidxT);
    scan1_kernel<<<dim3((NB + 255) / 256, L), 256, 0, stream>>>(pcnt, bstart);
    scan2_kernel<<<L, 1024, 0, stream>>>(bstart);
    sort2_kernel<<<dim3(NB, L), 256, 0, stream>>>(sidxT, pcnt, chunkoff, bstart,
                                                  edge_cols, edge_vals, cv, rowptr);

    for (int q = 0; q < 4; ++q) {
        gather_kernel<<<dim3(N / 4, L), 256, 0, stream>>>(xb, cv, rowptr, y, q);
        gemm_kernel<<<(N + 31) / 32, 256, 0, stream>>>(y, W, mix, bias, out, q);
    }
}

// Round 10
// 493.584 us; speedup vs baseline: 1.0860x; 1.0860x over previous
//
#include <hip/hip_runtime.h>

// AdaptiveGraphConvolution on MI355X (gfx950)
// out = sum_l m_l * (A_l @ x) @ W_l + bias
//
// R10: (1) sort pipeline carries payload, not indices: fill2 writes
// {cv=col|bf16val, rl} chunk-locally (private windows), sort2 pulls runs
// (no random col/val fetch; NCHK 100->50 doubles run length) and writes
// final CSR coalesced. (2) projection moved to MFMA: W pre-converted to
// transposed, mix-scaled bf16 (WbT, 128KB, L2-resident); gemm uses
// v_mfma_f32_16x16x32_bf16, out-RMW bound. ~45 MB workspace.

constexpr int N = 50000;
constexpr int E = 800000;
constexpr int D = 128;
constexpr int L = 4;
constexpr int BSH = 4;            // 16 rows per bucket
constexpr int NB = N >> BSH;      // 3125 buckets
constexpr int NCHK = 50;
constexpr int CHUNK = E / NCHK;   // 16000
constexpr int CAP = 1024;         // max bucket size in sort2 (mean 256)

typedef __attribute__((ext_vector_type(8))) short bf16x8;
typedef __attribute__((ext_vector_type(4))) float f32x4;
union U4B8 { uint4 u; bf16x8 b; };

__device__ inline unsigned bf16rne(unsigned u) {
    return (u + 0x7FFFu + ((u >> 16) & 1u)) >> 16;
}

// ---------------------------------------------------------------------------
// 0a) x -> 4 feature-sliced bf16 tables xb[q][row][fl].
// ---------------------------------------------------------------------------
__global__ __launch_bounds__(256) void cvt_x_kernel(
    const float* __restrict__ x, unsigned* __restrict__ xb)
{
    int i = blockIdx.x * 256 + threadIdx.x;     // 0 .. N*64
    int row = i >> 6, j = i & 63;
    int q = j >> 4, fl = j & 15;
    float2 v = *reinterpret_cast<const float2*>(x + (size_t)row * D + q * 32 + fl * 2);
    xb[((size_t)q * N + row) * 16 + fl] =
        bf16rne(__float_as_uint(v.x)) | (bf16rne(__float_as_uint(v.y)) << 16);
}

// ---------------------------------------------------------------------------
// 0b) W -> transposed, mix-scaled bf16: WbT[l][f][dpair] packs
//     (m_l*W[l][2dp][f], m_l*W[l][2dp+1][f]).  idx -> (l, dp, f), f fastest.
// ---------------------------------------------------------------------------
__global__ __launch_bounds__(256) void cvt_w_kernel(
    const float* __restrict__ W, const float* __restrict__ mix,
    unsigned* __restrict__ WbT)
{
    int idx = blockIdx.x * 256 + threadIdx.x;   // 0 .. L*64*128
    int f = idx & 127, dp = (idx >> 7) & 63, l = idx >> 13;
    float m = mix[l];
    float a = m * W[((size_t)l * D + 2 * dp) * D + f];
    float b = m * W[((size_t)l * D + 2 * dp + 1) * D + f];
    WbT[((size_t)l * D + f) * 64 + dp] =
        bf16rne(__float_as_uint(a)) | (bf16rne(__float_as_uint(b)) << 16);
}

// ---------------------------------------------------------------------------
// 1) fill2 (hist + chunk-local bucket sort of PAYLOAD), grid (NCHK, L):
//    writes pcnt counts, chunkoff, and {cvT, rlT} into the block-private
//    chunk window (full-line coverage, no write-allocate waste).
// ---------------------------------------------------------------------------
__global__ __launch_bounds__(256) void fill2_kernel(
    const int* __restrict__ edge_rows,
    const int* __restrict__ edge_cols,
    const float* __restrict__ edge_vals,
    unsigned short* __restrict__ pcnt,       // [L][NCHK][NB] counts out
    unsigned short* __restrict__ chunkoff,   // [L][NCHK][NB] local offsets out
    unsigned* __restrict__ cvT,              // [L][E] chunk-local payload
    unsigned char* __restrict__ rlT)         // [L][E] chunk-local row key
{
    __shared__ int cnt[NB];
    __shared__ int psum[256];
    const int blk = blockIdx.x, g = blockIdx.y, tid = threadIdx.x;

    for (int i = tid; i < NB; i += 256) cnt[i] = 0;
    __syncthreads();

    const size_t eoff = (size_t)g * E + (size_t)blk * CHUNK;
    const int* rows = edge_rows + eoff;
    const int* cols = edge_cols + eoff;
    const float* vals = edge_vals + eoff;

    for (int i = tid; i < CHUNK; i += 256)
        atomicAdd(&cnt[rows[i] >> BSH], 1);
    __syncthreads();

    unsigned short* pc = pcnt + ((size_t)g * NCHK + blk) * NB;
    for (int i = tid; i < NB; i += 256) pc[i] = (unsigned short)cnt[i];
    __syncthreads();

    // exclusive prefix over 3125 bins
    constexpr int CB = (NB + 255) / 256;   // 13
    const int base = tid * CB;
    int s = 0;
#pragma unroll
    for (int j = 0; j < CB; ++j) {
        int idx = base + j;
        if (idx < NB) s += cnt[idx];
    }
    psum[tid] = s;
    __syncthreads();
    for (int off = 1; off < 256; off <<= 1) {
        int v = (tid >= off) ? psum[tid - off] : 0;
        __syncthreads();
        psum[tid] += v;
        __syncthreads();
    }
    int carry = (tid == 0) ? 0 : psum[tid - 1];
#pragma unroll
    for (int j = 0; j < CB; ++j) {
        int idx = base + j;
        if (idx < NB) {
            int c = cnt[idx];
            cnt[idx] = carry;
            carry += c;
        }
    }
    __syncthreads();

    unsigned short* co = chunkoff + ((size_t)g * NCHK + blk) * NB;
    for (int i = tid; i < NB; i += 256) co[i] = (unsigned short)cnt[i];
    __syncthreads();

    // rank-scatter payload into the private window
    unsigned* cw = cvT + eoff;
    unsigned char* rw = rlT + eoff;
    for (int i = tid; i < CHUNK; i += 256) {
        int r = rows[i];
        int b = r >> BSH;
        int pos = atomicAdd(&cnt[b], 1);
        cw[pos] = (unsigned)cols[i] | (bf16rne(__float_as_uint(vals[i])) << 16);
        rw[pos] = (unsigned char)(r & 15);
    }
}

// ---------------------------------------------------------------------------
// 2a) Column pass: pcnt counts -> within-bucket cross-chunk offsets;
//     bucket totals -> bstart.
// ---------------------------------------------------------------------------
__global__ __launch_bounds__(256) void scan1_kernel(
    unsigned short* __restrict__ pcnt, int* __restrict__ bstart)
{
    const int b = blockIdx.x * 256 + threadIdx.x;
    const int g = blockIdx.y;
    if (b >= NB) return;
    unsigned run = 0;
    unsigned short* p = pcnt + (size_t)g * NCHK * NB + b;
    for (int blk = 0; blk < NCHK; ++blk) {
        unsigned v = p[(size_t)blk * NB];
        p[(size_t)blk * NB] = (unsigned short)run;
        run += v;
    }
    bstart[(size_t)g * (NB + 1) + b] = (int)run;
}

// ---------------------------------------------------------------------------
// 2b) Per-graph exclusive scan of bucket totals.
// ---------------------------------------------------------------------------
__global__ __launch_bounds__(1024) void scan2_kernel(int* __restrict__ bstart)
{
    __shared__ int sums[1024];
    int* bs = bstart + (size_t)blockIdx.x * (NB + 1);
    const int t = threadIdx.x;
    int tv[4];
    int s = 0;
#pragma unroll
    for (int i = 0; i < 4; ++i) {
        int idx = t * 4 + i;
        tv[i] = (idx < NB) ? bs[idx] : 0;
        s += tv[i];
    }
    sums[t] = s;
    __syncthreads();
    for (int off = 1; off < 1024; off <<= 1) {
        int v = (t >= off) ? sums[t - off] : 0;
        __syncthreads();
        sums[t] += v;
        __syncthreads();
    }
    int ex = (t == 0) ? 0 : sums[t - 1];
#pragma unroll
    for (int i = 0; i < 4; ++i) {
        int idx = t * 4 + i;
        if (idx < NB) { bs[idx] = ex; ex += tv[i]; }
    }
    if (t == 0) bs[NB] = E;
}

// ---------------------------------------------------------------------------
// 3) sort2 (pull payload), grid (NB, L): threads 0..NCHK-1 copy their
//    chunk's {cv, rl} run into LDS at canonical position; 16-bin counting
//    sort by rl; coalesced cv write + CSR rowptr. No random col/val reads.
// ---------------------------------------------------------------------------
__global__ __launch_bounds__(256) void sort2_kernel(
    const unsigned* __restrict__ cvT,            // [L][E]
    const unsigned char* __restrict__ rlT,       // [L][E]
    const unsigned short* __restrict__ pcnt,     // [L][NCHK][NB] offsets
    const unsigned short* __restrict__ chunkoff, // [L][NCHK][NB]
    const int* __restrict__ bstart,              // [L][NB+1]
    unsigned* __restrict__ cv,                   // [L][E] final
    int* __restrict__ rowptr)                    // [L][N+1]
{
    __shared__ unsigned su_cv[CAP], ss_cv[CAP];
    __shared__ unsigned char su_rl[CAP];
    __shared__ int rc[17], rcur[16];
    const int b = blockIdx.x, g = blockIdx.y, tid = threadIdx.x;
    const int beg = bstart[(size_t)g * (NB + 1) + b];
    const int tot = bstart[(size_t)g * (NB + 1) + b + 1] - beg;
    const int cnt = tot < CAP ? tot : CAP;
    int* rp = rowptr + (size_t)g * (N + 1);
    if (b == 0 && tid == 0) rp[N] = E;
    if (tid < 17) rc[tid] = 0;

    if (tid < NCHK) {
        const int c = tid;
        const size_t pbase = ((size_t)g * NCHK + c) * NB + b;
        int off = pcnt[pbase];
        int nxt = (c == NCHK - 1) ? tot : (int)pcnt[pbase + NB];
        int len = nxt - off;
        const size_t wbase = (size_t)g * E + (size_t)c * CHUNK + chunkoff[pbase];
        const unsigned* cw = cvT + wbase;
        const unsigned char* rw = rlT + wbase;
        for (int i = 0; i < len; ++i) {
            int p = off + i;
            if (p < CAP) { su_cv[p] = cw[i]; su_rl[p] = rw[i]; }
        }
    }
    __syncthreads();

    for (int i = tid; i < cnt; i += 256) atomicAdd(&rc[su_rl[i] + 1], 1);
    __syncthreads();
    if (tid == 0) {
        int run = 0;
#pragma unroll
        for (int r = 1; r <= 16; ++r) { run += rc[r]; rc[r] = run; }
    }
    __syncthreads();
    if (tid < 16) {
        rcur[tid] = rc[tid];
        rp[b * 16 + tid] = beg + rc[tid];
    }
    __syncthreads();
    for (int i = tid; i < cnt; i += 256) {
        int p = atomicAdd(&rcur[su_rl[i]], 1);
        ss_cv[p] = su_cv[i];
    }
    __syncthreads();
    unsigned* cvg = cv + (size_t)g * E;
    for (int i = tid; i < cnt; i += 256) cvg[beg + i] = ss_cv[i];
}

// ---------------------------------------------------------------------------
// 4) Sliced gather, pass q, grid (N/4, L): R8 structure (L2-resident 3.2MB
//    slice, batch-preload + shfl broadcast, branch-free padding).
// ---------------------------------------------------------------------------
__global__ __launch_bounds__(256) void gather_kernel(
    const unsigned* __restrict__ xb,      // [4][N][16]
    const unsigned* __restrict__ cv,      // [L][E]
    const int* __restrict__ rowptr,       // [L][N+1]
    unsigned* __restrict__ y,             // [L][N][16]
    int q)
{
    const int tid = threadIdx.x;
    const int row = blockIdx.x * 4 + (tid >> 6);
    const int l = blockIdx.y;
    const int lane = tid & 63;
    const int sub = lane >> 4, fl = lane & 15;

    const unsigned* xq = xb + (size_t)q * N * 16;
    const unsigned* cvg = cv + (size_t)l * E;
    const int* rp = rowptr + (size_t)l * (N + 1);

    const int beg = rp[row], end = rp[row + 1];
    float accx = 0.f, accy = 0.f;
    for (int base = beg; base < end; base += 64) {
        int cnt = end - base;
        if (cnt > 64) cnt = 64;
        unsigned cvr = (lane < cnt) ? cvg[base + lane] : 0u;
        const int nk = (cnt + 3) >> 2;
#pragma unroll 4
        for (int k = 0; k < nk; ++k) {
            unsigned c = __shfl(cvr, k * 4 + sub);
            float v = __uint_as_float(c & 0xFFFF0000u);   // padding -> +0.0
            unsigned col = c & 0xFFFFu;
            unsigned xv = xq[(size_t)col * 16 + fl];
            accx = fmaf(v, __uint_as_float(xv << 16), accx);
            accy = fmaf(v, __uint_as_float(xv & 0xFFFF0000u), accy);
        }
    }
    accx += __shfl_xor(accx, 16); accx += __shfl_xor(accx, 32);
    accy += __shfl_xor(accy, 16); accy += __shfl_xor(accy, 32);
    if (lane < 16)
        y[((size_t)l * N + row) * 16 + fl] =
            bf16rne(__float_as_uint(accx)) | (bf16rne(__float_as_uint(accy)) << 16);
}

// ---------------------------------------------------------------------------
// 5) MFMA K=32 GEMM-accumulate, pass q:
//    out[32-row tile][128] (+)= sum_l y_l[tile][32] @ (m_l W_l[slice q]).
//    Block = 256 thr = 4 waves; wave w: rows16=(w&1)*16, cols (w>>1)*64+{0..3}*16.
//    A: lane row=lane&15, k=(lane>>4)*8+j (uint4 from y). B: col=lane&15,
//    same k (uint4 from WbT). C/D: col=lane&15, row=(lane>>4)*4+reg.
// ---------------------------------------------------------------------------
__global__ __launch_bounds__(256) void gemm_mfma_kernel(
    const unsigned* __restrict__ y,      // [L][N][16]
    const unsigned* __restrict__ WbT,    // [L][128][64] bf16 pairs (scaled)
    const float* __restrict__ bias,
    float* __restrict__ out,
    int q)
{
    const int tid = threadIdx.x;
    const int lane = tid & 63, w = tid >> 6;
    const int r0 = blockIdx.x * 32;
    const int rows16 = (w & 1) * 16;
    const int fbase = (w >> 1) * 64;
    const int lrow = lane & 15, kgrp = lane >> 4;

    f32x4 acc[4] = {};
    const int arow = r0 + rows16 + lrow;

#pragma unroll
    for (int l = 0; l < L; ++l) {
        U4B8 a;
        a.u = (arow < N)
            ? *reinterpret_cast<const uint4*>(y + ((size_t)l * N + arow) * 16 + kgrp * 4)
            : make_uint4(0u, 0u, 0u, 0u);
#pragma unroll
        for (int t = 0; t < 4; ++t) {
            const int f = fbase + t * 16 + lrow;
            U4B8 bb;
            bb.u = *reinterpret_cast<const uint4*>(
                WbT + ((size_t)l * D + f) * 64 + q * 16 + kgrp * 4);
            acc[t] = __builtin_amdgcn_mfma_f32_16x16x32_bf16(a.b, bb.b, acc[t], 0, 0, 0);
        }
    }

#pragma unroll
    for (int t = 0; t < 4; ++t) {
        const int f = fbase + t * 16 + lrow;
#pragma unroll
        for (int i = 0; i < 4; ++i) {
            int row = r0 + rows16 + kgrp * 4 + i;
            if (row < N) {
                float* p = out + (size_t)row * D + f;
                float v = acc[t][i];
                *p = (q == 0) ? v + bias[f] : *p + v;
            }
        }
    }
}

extern "C" void kernel_launch(void* const* d_in, const int* in_sizes, int n_in,
                              void* d_out, int out_size, void* d_ws, size_t ws_size,
                              hipStream_t stream)
{
    const float* x         = (const float*)d_in[0];
    const int*   edge_rows = (const int*)d_in[1];
    const int*   edge_cols = (const int*)d_in[2];
    const float* edge_vals = (const float*)d_in[3];
    const float* W         = (const float*)d_in[4];
    const float* mix       = (const float*)d_in[5];
    const float* bias      = (const float*)d_in[6];
    float* out = (float*)d_out;

    // Workspace (~45.1 MB):
    // cvT [L][E] u32 (12.8M, y aliases after sort2) | rlT [L][E] u8 (3.2M) |
    // pcnt u16 (1.25M) | chunkoff u16 (1.25M) | bstart (50K) | rowptr (0.8M) |
    // cv [L][E] u32 (12.8M) | xb [4][N][16] (12.8M) | WbT [L][128][64] (128K)
    unsigned*       cvT      = (unsigned*)d_ws;
    unsigned char*  rlT      = (unsigned char*)(cvT + (size_t)L * E);
    unsigned short* pcnt     = (unsigned short*)(rlT + (size_t)L * E);
    unsigned short* chunkoff = pcnt + (size_t)L * NCHK * NB;
    int*            bstart   = (int*)(chunkoff + (size_t)L * NCHK * NB);
    int*            rowptr   = bstart + (size_t)L * (NB + 1);
    unsigned*       cv       = (unsigned*)(rowptr + (size_t)L * (N + 1));
    unsigned*       xb       = cv + (size_t)L * E;
    unsigned*       WbT      = xb + (size_t)4 * N * 16;
    unsigned*       y        = cvT;   // alias: cvT dead after sort2

    cvt_x_kernel<<<(N * 64) / 256, 256, 0, stream>>>(x, xb);
    cvt_w_kernel<<<(L * D * 64) / 256, 256, 0, stream>>>(W, mix, WbT);
    fill2_kernel<<<dim3(NCHK, L), 256, 0, stream>>>(edge_rows, edge_cols, edge_vals,
                                                    pcnt, chunkoff, cvT, rlT);
    scan1_kernel<<<dim3((NB + 255) / 256, L), 256, 0, stream>>>(pcnt, bstart);
    scan2_kernel<<<L, 1024, 0, stream>>>(bstart);
    sort2_kernel<<<dim3(NB, L), 256, 0, stream>>>(cvT, rlT, pcnt, chunkoff, bstart,
                                                  cv, rowptr);

    for (int q = 0; q < 4; ++q) {
        gather_kernel<<<dim3(N / 4, L), 256, 0, stream>>>(xb, cv, rowptr, y, q);
        gemm_mfma_kernel<<<(N + 31) / 32, 256, 0, stream>>>(y, WbT, bias, out, q);
    }
}

// Round 11
// 460.825 us; speedup vs baseline: 1.1632x; 1.0711x over previous
//
#include <hip/hip_runtime.h>

// AdaptiveGraphConvolution on MI355X (gfx950)
// out = sum_l m_l * (A_l @ x) @ W_l + bias
//
// R11: fill2's chunk-local sort staged in LDS (cv 32KB + rl 8KB), streamed
// out coalesced -- kills the 6x partial-line write-back amplification
// (R10: 127MB WRITE for 19MB payload) and restores parallelism
// (NCHK 50->100, 400 blocks vs 200). Rest unchanged from R10:
// payload-carrying two-level sort, L2-sliced decoupled gather, MFMA gemm.

constexpr int N = 50000;
constexpr int E = 800000;
constexpr int D = 128;
constexpr int L = 4;
constexpr int BSH = 4;            // 16 rows per bucket
constexpr int NB = N >> BSH;      // 3125 buckets
constexpr int NCHK = 100;
constexpr int CHUNK = E / NCHK;   // 8000
constexpr int CAP = 1024;         // max bucket size in sort2 (mean 256)

typedef __attribute__((ext_vector_type(8))) short bf16x8;
typedef __attribute__((ext_vector_type(4))) float f32x4;
union U4B8 { uint4 u; bf16x8 b; };

__device__ inline unsigned bf16rne(unsigned u) {
    return (u + 0x7FFFu + ((u >> 16) & 1u)) >> 16;
}

// ---------------------------------------------------------------------------
// 0a) x -> 4 feature-sliced bf16 tables xb[q][row][fl].
// ---------------------------------------------------------------------------
__global__ __launch_bounds__(256) void cvt_x_kernel(
    const float* __restrict__ x, unsigned* __restrict__ xb)
{
    int i = blockIdx.x * 256 + threadIdx.x;     // 0 .. N*64
    int row = i >> 6, j = i & 63;
    int q = j >> 4, fl = j & 15;
    float2 v = *reinterpret_cast<const float2*>(x + (size_t)row * D + q * 32 + fl * 2);
    xb[((size_t)q * N + row) * 16 + fl] =
        bf16rne(__float_as_uint(v.x)) | (bf16rne(__float_as_uint(v.y)) << 16);
}

// ---------------------------------------------------------------------------
// 0b) W -> transposed, mix-scaled bf16: WbT[l][f][dpair].
// ---------------------------------------------------------------------------
__global__ __launch_bounds__(256) void cvt_w_kernel(
    const float* __restrict__ W, const float* __restrict__ mix,
    unsigned* __restrict__ WbT)
{
    int idx = blockIdx.x * 256 + threadIdx.x;   // 0 .. L*64*128
    int f = idx & 127, dp = (idx >> 7) & 63, l = idx >> 13;
    float m = mix[l];
    float a = m * W[((size_t)l * D + 2 * dp) * D + f];
    float b = m * W[((size_t)l * D + 2 * dp + 1) * D + f];
    WbT[((size_t)l * D + f) * 64 + dp] =
        bf16rne(__float_as_uint(a)) | (bf16rne(__float_as_uint(b)) << 16);
}

// ---------------------------------------------------------------------------
// 1) fill2, grid (NCHK, L): LDS hist -> pcnt/chunkoff -> rank-scatter the
//    payload {cv, rl} INTO LDS -> coalesced copy-out to the chunk window.
//    Global writes are streaming, full-line covered. ~53.5KB LDS, 2 blk/CU.
// ---------------------------------------------------------------------------
__global__ __launch_bounds__(256) void fill2_kernel(
    const int* __restrict__ edge_rows,
    const int* __restrict__ edge_cols,
    const float* __restrict__ edge_vals,
    unsigned short* __restrict__ pcnt,       // [L][NCHK][NB] counts out
    unsigned short* __restrict__ chunkoff,   // [L][NCHK][NB] local offsets out
    unsigned* __restrict__ cvT,              // [L][E] chunk-local payload
    unsigned char* __restrict__ rlT)         // [L][E] chunk-local row key
{
    __shared__ int cnt[NB];                  // 12.5 KB
    __shared__ int psum[256];                // 1 KB
    __shared__ unsigned lcv[CHUNK];          // 32 KB
    __shared__ unsigned char lrl[CHUNK];     // 8 KB
    const int blk = blockIdx.x, g = blockIdx.y, tid = threadIdx.x;

    for (int i = tid; i < NB; i += 256) cnt[i] = 0;
    __syncthreads();

    const size_t eoff = (size_t)g * E + (size_t)blk * CHUNK;
    const int* rows = edge_rows + eoff;
    const int* cols = edge_cols + eoff;
    const float* vals = edge_vals + eoff;

    for (int i = tid; i < CHUNK; i += 256)
        atomicAdd(&cnt[rows[i] >> BSH], 1);
    __syncthreads();

    unsigned short* pc = pcnt + ((size_t)g * NCHK + blk) * NB;
    for (int i = tid; i < NB; i += 256) pc[i] = (unsigned short)cnt[i];
    __syncthreads();

    // exclusive prefix over 3125 bins
    constexpr int CB = (NB + 255) / 256;   // 13
    const int base = tid * CB;
    int s = 0;
#pragma unroll
    for (int j = 0; j < CB; ++j) {
        int idx = base + j;
        if (idx < NB) s += cnt[idx];
    }
    psum[tid] = s;
    __syncthreads();
    for (int off = 1; off < 256; off <<= 1) {
        int v = (tid >= off) ? psum[tid - off] : 0;
        __syncthreads();
        psum[tid] += v;
        __syncthreads();
    }
    int carry = (tid == 0) ? 0 : psum[tid - 1];
#pragma unroll
    for (int j = 0; j < CB; ++j) {
        int idx = base + j;
        if (idx < NB) {
            int c = cnt[idx];
            cnt[idx] = carry;
            carry += c;
        }
    }
    __syncthreads();

    unsigned short* co = chunkoff + ((size_t)g * NCHK + blk) * NB;
    for (int i = tid; i < NB; i += 256) co[i] = (unsigned short)cnt[i];
    __syncthreads();

    // rank-scatter payload into LDS (random LDS writes: no line granularity)
    for (int i = tid; i < CHUNK; i += 256) {
        int r = rows[i];
        int b = r >> BSH;
        int pos = atomicAdd(&cnt[b], 1);
        lcv[pos] = (unsigned)cols[i] | (bf16rne(__float_as_uint(vals[i])) << 16);
        lrl[pos] = (unsigned char)(r & 15);
    }
    __syncthreads();

    // coalesced copy-out (full-line streaming writes)
    unsigned* cw = cvT + eoff;
    unsigned char* rw = rlT + eoff;
    for (int i = tid; i < CHUNK; i += 256) cw[i] = lcv[i];
    for (int i = tid * 4; i < CHUNK; i += 1024)
        *reinterpret_cast<uint*>(rw + i) = *reinterpret_cast<const uint*>(lrl + i);
}

// ---------------------------------------------------------------------------
// 2a) Column pass: pcnt counts -> within-bucket cross-chunk offsets;
//     bucket totals -> bstart.
// ---------------------------------------------------------------------------
__global__ __launch_bounds__(256) void scan1_kernel(
    unsigned short* __restrict__ pcnt, int* __restrict__ bstart)
{
    const int b = blockIdx.x * 256 + threadIdx.x;
    const int g = blockIdx.y;
    if (b >= NB) return;
    unsigned run = 0;
    unsigned short* p = pcnt + (size_t)g * NCHK * NB + b;
    for (int blk = 0; blk < NCHK; ++blk) {
        unsigned v = p[(size_t)blk * NB];
        p[(size_t)blk * NB] = (unsigned short)run;
        run += v;
    }
    bstart[(size_t)g * (NB + 1) + b] = (int)run;
}

// ---------------------------------------------------------------------------
// 2b) Per-graph exclusive scan of bucket totals.
// ---------------------------------------------------------------------------
__global__ __launch_bounds__(1024) void scan2_kernel(int* __restrict__ bstart)
{
    __shared__ int sums[1024];
    int* bs = bstart + (size_t)blockIdx.x * (NB + 1);
    const int t = threadIdx.x;
    int tv[4];
    int s = 0;
#pragma unroll
    for (int i = 0; i < 4; ++i) {
        int idx = t * 4 + i;
        tv[i] = (idx < NB) ? bs[idx] : 0;
        s += tv[i];
    }
    sums[t] = s;
    __syncthreads();
    for (int off = 1; off < 1024; off <<= 1) {
        int v = (t >= off) ? sums[t - off] : 0;
        __syncthreads();
        sums[t] += v;
        __syncthreads();
    }
    int ex = (t == 0) ? 0 : sums[t - 1];
#pragma unroll
    for (int i = 0; i < 4; ++i) {
        int idx = t * 4 + i;
        if (idx < NB) { bs[idx] = ex; ex += tv[i]; }
    }
    if (t == 0) bs[NB] = E;
}

// ---------------------------------------------------------------------------
// 3) sort2 (pull payload), grid (NB, L): threads 0..NCHK-1 copy their
//    chunk's {cv, rl} run into LDS; 16-bin counting sort by rl; coalesced
//    cv write + CSR rowptr.
// ---------------------------------------------------------------------------
__global__ __launch_bounds__(256) void sort2_kernel(
    const unsigned* __restrict__ cvT,            // [L][E]
    const unsigned char* __restrict__ rlT,       // [L][E]
    const unsigned short* __restrict__ pcnt,     // [L][NCHK][NB] offsets
    const unsigned short* __restrict__ chunkoff, // [L][NCHK][NB]
    const int* __restrict__ bstart,              // [L][NB+1]
    unsigned* __restrict__ cv,                   // [L][E] final
    int* __restrict__ rowptr)                    // [L][N+1]
{
    __shared__ unsigned su_cv[CAP], ss_cv[CAP];
    __shared__ unsigned char su_rl[CAP];
    __shared__ int rc[17], rcur[16];
    const int b = blockIdx.x, g = blockIdx.y, tid = threadIdx.x;
    const int beg = bstart[(size_t)g * (NB + 1) + b];
    const int tot = bstart[(size_t)g * (NB + 1) + b + 1] - beg;
    const int cnt = tot < CAP ? tot : CAP;
    int* rp = rowptr + (size_t)g * (N + 1);
    if (b == 0 && tid == 0) rp[N] = E;
    if (tid < 17) rc[tid] = 0;

    if (tid < NCHK) {
        const int c = tid;
        const size_t pbase = ((size_t)g * NCHK + c) * NB + b;
        int off = pcnt[pbase];
        int nxt = (c == NCHK - 1) ? tot : (int)pcnt[pbase + NB];
        int len = nxt - off;
        const size_t wbase = (size_t)g * E + (size_t)c * CHUNK + chunkoff[pbase];
        const unsigned* cw = cvT + wbase;
        const unsigned char* rw = rlT + wbase;
        for (int i = 0; i < len; ++i) {
            int p = off + i;
            if (p < CAP) { su_cv[p] = cw[i]; su_rl[p] = rw[i]; }
        }
    }
    __syncthreads();

    for (int i = tid; i < cnt; i += 256) atomicAdd(&rc[su_rl[i] + 1], 1);
    __syncthreads();
    if (tid == 0) {
        int run = 0;
#pragma unroll
        for (int r = 1; r <= 16; ++r) { run += rc[r]; rc[r] = run; }
    }
    __syncthreads();
    if (tid < 16) {
        rcur[tid] = rc[tid];
        rp[b * 16 + tid] = beg + rc[tid];
    }
    __syncthreads();
    for (int i = tid; i < cnt; i += 256) {
        int p = atomicAdd(&rcur[su_rl[i]], 1);
        ss_cv[p] = su_cv[i];
    }
    __syncthreads();
    unsigned* cvg = cv + (size_t)g * E;
    for (int i = tid; i < cnt; i += 256) cvg[beg + i] = ss_cv[i];
}

// ---------------------------------------------------------------------------
// 4) Sliced gather, pass q, grid (N/4, L): L2-resident 3.2MB slice,
//    batch-preload + shfl broadcast, branch-free padding.
// ---------------------------------------------------------------------------
__global__ __launch_bounds__(256) void gather_kernel(
    const unsigned* __restrict__ xb,      // [4][N][16]
    const unsigned* __restrict__ cv,      // [L][E]
    const int* __restrict__ rowptr,       // [L][N+1]
    unsigned* __restrict__ y,             // [L][N][16]
    int q)
{
    const int tid = threadIdx.x;
    const int row = blockIdx.x * 4 + (tid >> 6);
    const int l = blockIdx.y;
    const int lane = tid & 63;
    const int sub = lane >> 4, fl = lane & 15;

    const unsigned* xq = xb + (size_t)q * N * 16;
    const unsigned* cvg = cv + (size_t)l * E;
    const int* rp = rowptr + (size_t)l * (N + 1);

    const int beg = rp[row], end = rp[row + 1];
    float accx = 0.f, accy = 0.f;
    for (int base = beg; base < end; base += 64) {
        int cnt = end - base;
        if (cnt > 64) cnt = 64;
        unsigned cvr = (lane < cnt) ? cvg[base + lane] : 0u;
        const int nk = (cnt + 3) >> 2;
#pragma unroll 4
        for (int k = 0; k < nk; ++k) {
            unsigned c = __shfl(cvr, k * 4 + sub);
            float v = __uint_as_float(c & 0xFFFF0000u);   // padding -> +0.0
            unsigned col = c & 0xFFFFu;
            unsigned xv = xq[(size_t)col * 16 + fl];
            accx = fmaf(v, __uint_as_float(xv << 16), accx);
            accy = fmaf(v, __uint_as_float(xv & 0xFFFF0000u), accy);
        }
    }
    accx += __shfl_xor(accx, 16); accx += __shfl_xor(accx, 32);
    accy += __shfl_xor(accy, 16); accy += __shfl_xor(accy, 32);
    if (lane < 16)
        y[((size_t)l * N + row) * 16 + fl] =
            bf16rne(__float_as_uint(accx)) | (bf16rne(__float_as_uint(accy)) << 16);
}

// ---------------------------------------------------------------------------
// 5) MFMA K=32 GEMM-accumulate, pass q (R10 structure).
// ---------------------------------------------------------------------------
__global__ __launch_bounds__(256) void gemm_mfma_kernel(
    const unsigned* __restrict__ y,      // [L][N][16]
    const unsigned* __restrict__ WbT,    // [L][128][64] bf16 pairs (scaled)
    const float* __restrict__ bias,
    float* __restrict__ out,
    int q)
{
    const int tid = threadIdx.x;
    const int lane = tid & 63, w = tid >> 6;
    const int r0 = blockIdx.x * 32;
    const int rows16 = (w & 1) * 16;
    const int fbase = (w >> 1) * 64;
    const int lrow = lane & 15, kgrp = lane >> 4;

    f32x4 acc[4] = {};
    const int arow = r0 + rows16 + lrow;

#pragma unroll
    for (int l = 0; l < L; ++l) {
        U4B8 a;
        a.u = (arow < N)
            ? *reinterpret_cast<const uint4*>(y + ((size_t)l * N + arow) * 16 + kgrp * 4)
            : make_uint4(0u, 0u, 0u, 0u);
#pragma unroll
        for (int t = 0; t < 4; ++t) {
            const int f = fbase + t * 16 + lrow;
            U4B8 bb;
            bb.u = *reinterpret_cast<const uint4*>(
                WbT + ((size_t)l * D + f) * 64 + q * 16 + kgrp * 4);
            acc[t] = __builtin_amdgcn_mfma_f32_16x16x32_bf16(a.b, bb.b, acc[t], 0, 0, 0);
        }
    }

#pragma unroll
    for (int t = 0; t < 4; ++t) {
        const int f = fbase + t * 16 + lrow;
#pragma unroll
        for (int i = 0; i < 4; ++i) {
            int row = r0 + rows16 + kgrp * 4 + i;
            if (row < N) {
                float* p = out + (size_t)row * D + f;
                float v = acc[t][i];
                *p = (q == 0) ? v + bias[f] : *p + v;
            }
        }
    }
}

extern "C" void kernel_launch(void* const* d_in, const int* in_sizes, int n_in,
                              void* d_out, int out_size, void* d_ws, size_t ws_size,
                              hipStream_t stream)
{
    const float* x         = (const float*)d_in[0];
    const int*   edge_rows = (const int*)d_in[1];
    const int*   edge_cols = (const int*)d_in[2];
    const float* edge_vals = (const float*)d_in[3];
    const float* W         = (const float*)d_in[4];
    const float* mix       = (const float*)d_in[5];
    const float* bias      = (const float*)d_in[6];
    float* out = (float*)d_out;

    // Workspace (~47.6 MB):
    // cvT [L][E] u32 (12.8M, y aliases after sort2) | rlT [L][E] u8 (3.2M) |
    // pcnt u16 (2.5M) | chunkoff u16 (2.5M) | bstart (50K) | rowptr (0.8M) |
    // cv [L][E] u32 (12.8M) | xb [4][N][16] (12.8M) | WbT (128K)
    unsigned*       cvT      = (unsigned*)d_ws;
    unsigned char*  rlT      = (unsigned char*)(cvT + (size_t)L * E);
    unsigned short* pcnt     = (unsigned short*)(rlT + (size_t)L * E);
    unsigned short* chunkoff = pcnt + (size_t)L * NCHK * NB;
    int*            bstart   = (int*)(chunkoff + (size_t)L * NCHK * NB);
    int*            rowptr   = bstart + (size_t)L * (NB + 1);
    unsigned*       cv       = (unsigned*)(rowptr + (size_t)L * (N + 1));
    unsigned*       xb       = cv + (size_t)L * E;
    unsigned*       WbT      = xb + (size_t)4 * N * 16;
    unsigned*       y        = cvT;   // alias: cvT dead after sort2

    cvt_x_kernel<<<(N * 64) / 256, 256, 0, stream>>>(x, xb);
    cvt_w_kernel<<<(L * D * 64) / 256, 256, 0, stream>>>(W, mix, WbT);
    fill2_kernel<<<dim3(NCHK, L), 256, 0, stream>>>(edge_rows, edge_cols, edge_vals,
                                                    pcnt, chunkoff, cvT, rlT);
    scan1_kernel<<<dim3((NB + 255) / 256, L), 256, 0, stream>>>(pcnt, bstart);
    scan2_kernel<<<L, 1024, 0, stream>>>(bstart);
    sort2_kernel<<<dim3(NB, L), 256, 0, stream>>>(cvT, rlT, pcnt, chunkoff, bstart,
                                                  cv, rowptr);

    for (int q = 0; q < 4; ++q) {
        gather_kernel<<<dim3(N / 4, L), 256, 0, stream>>>(xb, cv, rowptr, y, q);
        gemm_mfma_kernel<<<(N + 31) / 32, 256, 0, stream>>>(y, WbT, bias, out, q);
    }
}

// Round 12
// 316.361 us; speedup vs baseline: 1.6944x; 1.4566x over previous
//
#include <hip/hip_runtime.h>

// AdaptiveGraphConvolution on MI355X (gfx950)
// out = sum_l m_l * (A_l @ x) @ W_l + bias
//
// R12: gather restructured for memory-level parallelism. R11 evidence:
// slicing cut FETCH 198->28MB but dur didn't move (68us) -> chain-latency
// bound (runtime nk loop serializes the 4 xq loads; 1 row/wave = no ILP).
// Now: each 16-lane SUB owns a row (4 rows/wave), branch-free fully-unrolled
// 16-slot body -> 16 independent shfls + 16 independent xq loads per sub
// (up to 64 in flight per wave), no cross-sub fold. Rest = R11.

constexpr int N = 50000;
constexpr int E = 800000;
constexpr int D = 128;
constexpr int L = 4;
constexpr int BSH = 4;            // 16 rows per bucket
constexpr int NB = N >> BSH;      // 3125 buckets
constexpr int NCHK = 100;
constexpr int CHUNK = E / NCHK;   // 8000
constexpr int CAP = 1024;         // max bucket size in sort2 (mean 256)

typedef __attribute__((ext_vector_type(8))) short bf16x8;
typedef __attribute__((ext_vector_type(4))) float f32x4;
union U4B8 { uint4 u; bf16x8 b; };

__device__ inline unsigned bf16rne(unsigned u) {
    return (u + 0x7FFFu + ((u >> 16) & 1u)) >> 16;
}

// ---------------------------------------------------------------------------
// 0a) x -> 4 feature-sliced bf16 tables xb[q][row][fl].
// ---------------------------------------------------------------------------
__global__ __launch_bounds__(256) void cvt_x_kernel(
    const float* __restrict__ x, unsigned* __restrict__ xb)
{
    int i = blockIdx.x * 256 + threadIdx.x;     // 0 .. N*64
    int row = i >> 6, j = i & 63;
    int q = j >> 4, fl = j & 15;
    float2 v = *reinterpret_cast<const float2*>(x + (size_t)row * D + q * 32 + fl * 2);
    xb[((size_t)q * N + row) * 16 + fl] =
        bf16rne(__float_as_uint(v.x)) | (bf16rne(__float_as_uint(v.y)) << 16);
}

// ---------------------------------------------------------------------------
// 0b) W -> transposed, mix-scaled bf16: WbT[l][f][dpair].
// ---------------------------------------------------------------------------
__global__ __launch_bounds__(256) void cvt_w_kernel(
    const float* __restrict__ W, const float* __restrict__ mix,
    unsigned* __restrict__ WbT)
{
    int idx = blockIdx.x * 256 + threadIdx.x;   // 0 .. L*64*128
    int f = idx & 127, dp = (idx >> 7) & 63, l = idx >> 13;
    float m = mix[l];
    float a = m * W[((size_t)l * D + 2 * dp) * D + f];
    float b = m * W[((size_t)l * D + 2 * dp + 1) * D + f];
    WbT[((size_t)l * D + f) * 64 + dp] =
        bf16rne(__float_as_uint(a)) | (bf16rne(__float_as_uint(b)) << 16);
}

// ---------------------------------------------------------------------------
// 1) fill2, grid (NCHK, L): LDS hist -> pcnt/chunkoff -> rank-scatter the
//    payload {cv, rl} into LDS -> coalesced copy-out (R11, unchanged).
// ---------------------------------------------------------------------------
__global__ __launch_bounds__(256) void fill2_kernel(
    const int* __restrict__ edge_rows,
    const int* __restrict__ edge_cols,
    const float* __restrict__ edge_vals,
    unsigned short* __restrict__ pcnt,       // [L][NCHK][NB] counts out
    unsigned short* __restrict__ chunkoff,   // [L][NCHK][NB] local offsets out
    unsigned* __restrict__ cvT,              // [L][E] chunk-local payload
    unsigned char* __restrict__ rlT)         // [L][E] chunk-local row key
{
    __shared__ int cnt[NB];                  // 12.5 KB
    __shared__ int psum[256];                // 1 KB
    __shared__ unsigned lcv[CHUNK];          // 32 KB
    __shared__ unsigned char lrl[CHUNK];     // 8 KB
    const int blk = blockIdx.x, g = blockIdx.y, tid = threadIdx.x;

    for (int i = tid; i < NB; i += 256) cnt[i] = 0;
    __syncthreads();

    const size_t eoff = (size_t)g * E + (size_t)blk * CHUNK;
    const int* rows = edge_rows + eoff;
    const int* cols = edge_cols + eoff;
    const float* vals = edge_vals + eoff;

    for (int i = tid; i < CHUNK; i += 256)
        atomicAdd(&cnt[rows[i] >> BSH], 1);
    __syncthreads();

    unsigned short* pc = pcnt + ((size_t)g * NCHK + blk) * NB;
    for (int i = tid; i < NB; i += 256) pc[i] = (unsigned short)cnt[i];
    __syncthreads();

    constexpr int CB = (NB + 255) / 256;   // 13
    const int base = tid * CB;
    int s = 0;
#pragma unroll
    for (int j = 0; j < CB; ++j) {
        int idx = base + j;
        if (idx < NB) s += cnt[idx];
    }
    psum[tid] = s;
    __syncthreads();
    for (int off = 1; off < 256; off <<= 1) {
        int v = (tid >= off) ? psum[tid - off] : 0;
        __syncthreads();
        psum[tid] += v;
        __syncthreads();
    }
    int carry = (tid == 0) ? 0 : psum[tid - 1];
#pragma unroll
    for (int j = 0; j < CB; ++j) {
        int idx = base + j;
        if (idx < NB) {
            int c = cnt[idx];
            cnt[idx] = carry;
            carry += c;
        }
    }
    __syncthreads();

    unsigned short* co = chunkoff + ((size_t)g * NCHK + blk) * NB;
    for (int i = tid; i < NB; i += 256) co[i] = (unsigned short)cnt[i];
    __syncthreads();

    for (int i = tid; i < CHUNK; i += 256) {
        int r = rows[i];
        int b = r >> BSH;
        int pos = atomicAdd(&cnt[b], 1);
        lcv[pos] = (unsigned)cols[i] | (bf16rne(__float_as_uint(vals[i])) << 16);
        lrl[pos] = (unsigned char)(r & 15);
    }
    __syncthreads();

    unsigned* cw = cvT + eoff;
    unsigned char* rw = rlT + eoff;
    for (int i = tid; i < CHUNK; i += 256) cw[i] = lcv[i];
    for (int i = tid * 4; i < CHUNK; i += 1024)
        *reinterpret_cast<uint*>(rw + i) = *reinterpret_cast<const uint*>(lrl + i);
}

// ---------------------------------------------------------------------------
// 2a) Column pass: pcnt counts -> within-bucket cross-chunk offsets;
//     bucket totals -> bstart.
// ---------------------------------------------------------------------------
__global__ __launch_bounds__(256) void scan1_kernel(
    unsigned short* __restrict__ pcnt, int* __restrict__ bstart)
{
    const int b = blockIdx.x * 256 + threadIdx.x;
    const int g = blockIdx.y;
    if (b >= NB) return;
    unsigned run = 0;
    unsigned short* p = pcnt + (size_t)g * NCHK * NB + b;
    for (int blk = 0; blk < NCHK; ++blk) {
        unsigned v = p[(size_t)blk * NB];
        p[(size_t)blk * NB] = (unsigned short)run;
        run += v;
    }
    bstart[(size_t)g * (NB + 1) + b] = (int)run;
}

// ---------------------------------------------------------------------------
// 2b) Per-graph exclusive scan of bucket totals.
// ---------------------------------------------------------------------------
__global__ __launch_bounds__(1024) void scan2_kernel(int* __restrict__ bstart)
{
    __shared__ int sums[1024];
    int* bs = bstart + (size_t)blockIdx.x * (NB + 1);
    const int t = threadIdx.x;
    int tv[4];
    int s = 0;
#pragma unroll
    for (int i = 0; i < 4; ++i) {
        int idx = t * 4 + i;
        tv[i] = (idx < NB) ? bs[idx] : 0;
        s += tv[i];
    }
    sums[t] = s;
    __syncthreads();
    for (int off = 1; off < 1024; off <<= 1) {
        int v = (t >= off) ? sums[t - off] : 0;
        __syncthreads();
        sums[t] += v;
        __syncthreads();
    }
    int ex = (t == 0) ? 0 : sums[t - 1];
#pragma unroll
    for (int i = 0; i < 4; ++i) {
        int idx = t * 4 + i;
        if (idx < NB) { bs[idx] = ex; ex += tv[i]; }
    }
    if (t == 0) bs[NB] = E;
}

// ---------------------------------------------------------------------------
// 3) sort2 (pull payload), grid (NB, L) (R11, unchanged).
// ---------------------------------------------------------------------------
__global__ __launch_bounds__(256) void sort2_kernel(
    const unsigned* __restrict__ cvT,            // [L][E]
    const unsigned char* __restrict__ rlT,       // [L][E]
    const unsigned short* __restrict__ pcnt,     // [L][NCHK][NB] offsets
    const unsigned short* __restrict__ chunkoff, // [L][NCHK][NB]
    const int* __restrict__ bstart,              // [L][NB+1]
    unsigned* __restrict__ cv,                   // [L][E] final
    int* __restrict__ rowptr)                    // [L][N+1]
{
    __shared__ unsigned su_cv[CAP], ss_cv[CAP];
    __shared__ unsigned char su_rl[CAP];
    __shared__ int rc[17], rcur[16];
    const int b = blockIdx.x, g = blockIdx.y, tid = threadIdx.x;
    const int beg = bstart[(size_t)g * (NB + 1) + b];
    const int tot = bstart[(size_t)g * (NB + 1) + b + 1] - beg;
    const int cnt = tot < CAP ? tot : CAP;
    int* rp = rowptr + (size_t)g * (N + 1);
    if (b == 0 && tid == 0) rp[N] = E;
    if (tid < 17) rc[tid] = 0;

    if (tid < NCHK) {
        const int c = tid;
        const size_t pbase = ((size_t)g * NCHK + c) * NB + b;
        int off = pcnt[pbase];
        int nxt = (c == NCHK - 1) ? tot : (int)pcnt[pbase + NB];
        int len = nxt - off;
        const size_t wbase = (size_t)g * E + (size_t)c * CHUNK + chunkoff[pbase];
        const unsigned* cw = cvT + wbase;
        const unsigned char* rw = rlT + wbase;
        for (int i = 0; i < len; ++i) {
            int p = off + i;
            if (p < CAP) { su_cv[p] = cw[i]; su_rl[p] = rw[i]; }
        }
    }
    __syncthreads();

    for (int i = tid; i < cnt; i += 256) atomicAdd(&rc[su_rl[i] + 1], 1);
    __syncthreads();
    if (tid == 0) {
        int run = 0;
#pragma unroll
        for (int r = 1; r <= 16; ++r) { run += rc[r]; rc[r] = run; }
    }
    __syncthreads();
    if (tid < 16) {
        rcur[tid] = rc[tid];
        rp[b * 16 + tid] = beg + rc[tid];
    }
    __syncthreads();
    for (int i = tid; i < cnt; i += 256) {
        int p = atomicAdd(&rcur[su_rl[i]], 1);
        ss_cv[p] = su_cv[i];
    }
    __syncthreads();
    unsigned* cvg = cv + (size_t)g * E;
    for (int i = tid; i < cnt; i += 256) cvg[beg + i] = ss_cv[i];
}

// ---------------------------------------------------------------------------
// 4) Sliced gather, pass q, grid (N/16, L): each 16-lane SUB owns one row
//    (4 rows/wave, 16 rows/block). Per 16-edge batch: one coalesced cv read,
//    then a branch-free fully-unrolled 16-slot body (padding: v=+0, col=0).
//    16 independent shfls + 16 independent xq loads per sub; no fold.
// ---------------------------------------------------------------------------
__global__ __launch_bounds__(256) void gather_kernel(
    const unsigned* __restrict__ xb,      // [4][N][16]
    const unsigned* __restrict__ cv,      // [L][E]
    const int* __restrict__ rowptr,       // [L][N+1]
    unsigned* __restrict__ y,             // [L][N][16]
    int q)
{
    const int tid = threadIdx.x;
    const int lane = tid & 63;
    const int wave = tid >> 6;
    const int sub = lane >> 4;            // 0..3: which row of the wave
    const int fl = lane & 15;
    const int subbase = lane & 48;        // sub*16, shfl base
    const int row = blockIdx.x * 16 + wave * 4 + sub;
    const int l = blockIdx.y;

    const unsigned* xq = xb + (size_t)q * N * 16;
    const unsigned* cvg = cv + (size_t)l * E;
    const int* rp = rowptr + (size_t)l * (N + 1);

    const int beg = rp[row], end = rp[row + 1];
    float accx = 0.f, accy = 0.f;

    for (int base = beg; base < end; base += 16) {
        const int cnt = end - base;                       // uniform within sub
        unsigned cvr = (fl < cnt) ? cvg[base + fl] : 0u;  // 64B/sub coalesced
#pragma unroll
        for (int k = 0; k < 16; k += 4) {
            unsigned c0 = __shfl(cvr, subbase + k + 0);
            unsigned c1 = __shfl(cvr, subbase + k + 1);
            unsigned c2 = __shfl(cvr, subbase + k + 2);
            unsigned c3 = __shfl(cvr, subbase + k + 3);
            unsigned x0 = xq[(size_t)(c0 & 0xFFFFu) * 16 + fl];
            unsigned x1 = xq[(size_t)(c1 & 0xFFFFu) * 16 + fl];
            unsigned x2 = xq[(size_t)(c2 & 0xFFFFu) * 16 + fl];
            unsigned x3 = xq[(size_t)(c3 & 0xFFFFu) * 16 + fl];
            float v0 = __uint_as_float(c0 & 0xFFFF0000u);  // padding -> +0.0
            float v1 = __uint_as_float(c1 & 0xFFFF0000u);
            float v2 = __uint_as_float(c2 & 0xFFFF0000u);
            float v3 = __uint_as_float(c3 & 0xFFFF0000u);
            accx = fmaf(v0, __uint_as_float(x0 << 16), accx);
            accy = fmaf(v0, __uint_as_float(x0 & 0xFFFF0000u), accy);
            accx = fmaf(v1, __uint_as_float(x1 << 16), accx);
            accy = fmaf(v1, __uint_as_float(x1 & 0xFFFF0000u), accy);
            accx = fmaf(v2, __uint_as_float(x2 << 16), accx);
            accy = fmaf(v2, __uint_as_float(x2 & 0xFFFF0000u), accy);
            accx = fmaf(v3, __uint_as_float(x3 << 16), accx);
            accy = fmaf(v3, __uint_as_float(x3 & 0xFFFF0000u), accy);
        }
    }

    y[((size_t)l * N + row) * 16 + fl] =
        bf16rne(__float_as_uint(accx)) | (bf16rne(__float_as_uint(accy)) << 16);
}

// ---------------------------------------------------------------------------
// 5) MFMA K=32 GEMM-accumulate, pass q (R10 structure, unchanged).
// ---------------------------------------------------------------------------
__global__ __launch_bounds__(256) void gemm_mfma_kernel(
    const unsigned* __restrict__ y,      // [L][N][16]
    const unsigned* __restrict__ WbT,    // [L][128][64] bf16 pairs (scaled)
    const float* __restrict__ bias,
    float* __restrict__ out,
    int q)
{
    const int tid = threadIdx.x;
    const int lane = tid & 63, w = tid >> 6;
    const int r0 = blockIdx.x * 32;
    const int rows16 = (w & 1) * 16;
    const int fbase = (w >> 1) * 64;
    const int lrow = lane & 15, kgrp = lane >> 4;

    f32x4 acc[4] = {};
    const int arow = r0 + rows16 + lrow;

#pragma unroll
    for (int l = 0; l < L; ++l) {
        U4B8 a;
        a.u = (arow < N)
            ? *reinterpret_cast<const uint4*>(y + ((size_t)l * N + arow) * 16 + kgrp * 4)
            : make_uint4(0u, 0u, 0u, 0u);
#pragma unroll
        for (int t = 0; t < 4; ++t) {
            const int f = fbase + t * 16 + lrow;
            U4B8 bb;
            bb.u = *reinterpret_cast<const uint4*>(
                WbT + ((size_t)l * D + f) * 64 + q * 16 + kgrp * 4);
            acc[t] = __builtin_amdgcn_mfma_f32_16x16x32_bf16(a.b, bb.b, acc[t], 0, 0, 0);
        }
    }

#pragma unroll
    for (int t = 0; t < 4; ++t) {
        const int f = fbase + t * 16 + lrow;
#pragma unroll
        for (int i = 0; i < 4; ++i) {
            int row = r0 + rows16 + kgrp * 4 + i;
            if (row < N) {
                float* p = out + (size_t)row * D + f;
                float v = acc[t][i];
                *p = (q == 0) ? v + bias[f] : *p + v;
            }
        }
    }
}

extern "C" void kernel_launch(void* const* d_in, const int* in_sizes, int n_in,
                              void* d_out, int out_size, void* d_ws, size_t ws_size,
                              hipStream_t stream)
{
    const float* x         = (const float*)d_in[0];
    const int*   edge_rows = (const int*)d_in[1];
    const int*   edge_cols = (const int*)d_in[2];
    const float* edge_vals = (const float*)d_in[3];
    const float* W         = (const float*)d_in[4];
    const float* mix       = (const float*)d_in[5];
    const float* bias      = (const float*)d_in[6];
    float* out = (float*)d_out;

    // Workspace (~47.6 MB), layout as R11:
    // cvT [L][E] u32 (12.8M, y aliases after sort2) | rlT [L][E] u8 (3.2M) |
    // pcnt u16 (2.5M) | chunkoff u16 (2.5M) | bstart (50K) | rowptr (0.8M) |
    // cv [L][E] u32 (12.8M) | xb [4][N][16] (12.8M) | WbT (128K)
    unsigned*       cvT      = (unsigned*)d_ws;
    unsigned char*  rlT      = (unsigned char*)(cvT + (size_t)L * E);
    unsigned short* pcnt     = (unsigned short*)(rlT + (size_t)L * E);
    unsigned short* chunkoff = pcnt + (size_t)L * NCHK * NB;
    int*            bstart   = (int*)(chunkoff + (size_t)L * NCHK * NB);
    int*            rowptr   = bstart + (size_t)L * (NB + 1);
    unsigned*       cv       = (unsigned*)(rowptr + (size_t)L * (N + 1));
    unsigned*       xb       = cv + (size_t)L * E;
    unsigned*       WbT      = xb + (size_t)4 * N * 16;
    unsigned*       y        = cvT;   // alias: cvT dead after sort2

    cvt_x_kernel<<<(N * 64) / 256, 256, 0, stream>>>(x, xb);
    cvt_w_kernel<<<(L * D * 64) / 256, 256, 0, stream>>>(W, mix, WbT);
    fill2_kernel<<<dim3(NCHK, L), 256, 0, stream>>>(edge_rows, edge_cols, edge_vals,
                                                    pcnt, chunkoff, cvT, rlT);
    scan1_kernel<<<dim3((NB + 255) / 256, L), 256, 0, stream>>>(pcnt, bstart);
    scan2_kernel<<<L, 1024, 0, stream>>>(bstart);
    sort2_kernel<<<dim3(NB, L), 256, 0, stream>>>(cvT, rlT, pcnt, chunkoff, bstart,
                                                  cv, rowptr);

    for (int q = 0; q < 4; ++q) {
        gather_kernel<<<dim3(N / 16, L), 256, 0, stream>>>(xb, cv, rowptr, y, q);
        gemm_mfma_kernel<<<(N + 31) / 32, 256, 0, stream>>>(y, WbT, bias, out, q);
    }
}

// Round 13
// 303.856 us; speedup vs baseline: 1.7641x; 1.0412x over previous
//
#include <hip/hip_runtime.h>

// AdaptiveGraphConvolution on MI355X (gfx950)
// out = sum_l m_l * (A_l @ x) @ W_l + bias
//
// R13: (1) fill2 split into hist (13.5KB LDS, high occupancy) + scatter
// (46.3KB, packed-u16 cursors) -- R12's fill2 was latency-bound at 14%
// occupancy. (2) MFMA projection FUSED into the gather: per q, block owns
// 16 rows; per graph, waves gather 4 rows each -> 1KB LDS bf16 tile ->
// 2 MFMAs/wave accumulating over graphs in registers; one out RMW per q.
// y buffer and 4 gemm launches eliminated. ~47.6 MB workspace.

constexpr int N = 50000;
constexpr int E = 800000;
constexpr int D = 128;
constexpr int L = 4;
constexpr int BSH = 4;            // 16 rows per bucket
constexpr int NB = N >> BSH;      // 3125 buckets
constexpr int NCHK = 100;
constexpr int CHUNK = E / NCHK;   // 8000
constexpr int CAP = 1024;         // max bucket size in sort2 (mean 256)

typedef __attribute__((ext_vector_type(8))) short bf16x8;
typedef __attribute__((ext_vector_type(4))) float f32x4;
union U4B8 { uint4 u; bf16x8 b; };

__device__ inline unsigned bf16rne(unsigned u) {
    return (u + 0x7FFFu + ((u >> 16) & 1u)) >> 16;
}

// ---------------------------------------------------------------------------
// 0a) x -> 4 feature-sliced bf16 tables xb[q][row][fl].
// ---------------------------------------------------------------------------
__global__ __launch_bounds__(256) void cvt_x_kernel(
    const float* __restrict__ x, unsigned* __restrict__ xb)
{
    int i = blockIdx.x * 256 + threadIdx.x;     // 0 .. N*64
    int row = i >> 6, j = i & 63;
    int q = j >> 4, fl = j & 15;
    float2 v = *reinterpret_cast<const float2*>(x + (size_t)row * D + q * 32 + fl * 2);
    xb[((size_t)q * N + row) * 16 + fl] =
        bf16rne(__float_as_uint(v.x)) | (bf16rne(__float_as_uint(v.y)) << 16);
}

// ---------------------------------------------------------------------------
// 0b) W -> transposed, mix-scaled bf16: WbT[l][f][dpair].
// ---------------------------------------------------------------------------
__global__ __launch_bounds__(256) void cvt_w_kernel(
    const float* __restrict__ W, const float* __restrict__ mix,
    unsigned* __restrict__ WbT)
{
    int idx = blockIdx.x * 256 + threadIdx.x;   // 0 .. L*64*128
    int f = idx & 127, dp = (idx >> 7) & 63, l = idx >> 13;
    float m = mix[l];
    float a = m * W[((size_t)l * D + 2 * dp) * D + f];
    float b = m * W[((size_t)l * D + 2 * dp + 1) * D + f];
    WbT[((size_t)l * D + f) * 64 + dp] =
        bf16rne(__float_as_uint(a)) | (bf16rne(__float_as_uint(b)) << 16);
}

// ---------------------------------------------------------------------------
// 1a) hist, grid (NCHK, L): LDS hist over 3125 buckets -> pcnt counts +
//     chunk-local exclusive prefix (chunkoff). 13.5KB LDS.
// ---------------------------------------------------------------------------
__global__ __launch_bounds__(256) void hist_kernel(
    const int* __restrict__ edge_rows,
    unsigned short* __restrict__ pcnt,       // [L][NCHK][NB] counts out
    unsigned short* __restrict__ chunkoff)   // [L][NCHK][NB] local offsets out
{
    __shared__ int cnt[NB];                  // 12.5 KB
    __shared__ int psum[256];                // 1 KB
    const int blk = blockIdx.x, g = blockIdx.y, tid = threadIdx.x;

    for (int i = tid; i < NB; i += 256) cnt[i] = 0;
    __syncthreads();

    const int* rows = edge_rows + (size_t)g * E + (size_t)blk * CHUNK;
    for (int i = tid; i < CHUNK; i += 256)
        atomicAdd(&cnt[rows[i] >> BSH], 1);
    __syncthreads();

    unsigned short* pc = pcnt + ((size_t)g * NCHK + blk) * NB;
    for (int i = tid; i < NB; i += 256) pc[i] = (unsigned short)cnt[i];
    __syncthreads();

    constexpr int CB = (NB + 255) / 256;   // 13
    const int base = tid * CB;
    int s = 0;
#pragma unroll
    for (int j = 0; j < CB; ++j) {
        int idx = base + j;
        if (idx < NB) s += cnt[idx];
    }
    psum[tid] = s;
    __syncthreads();
    for (int off = 1; off < 256; off <<= 1) {
        int v = (tid >= off) ? psum[tid - off] : 0;
        __syncthreads();
        psum[tid] += v;
        __syncthreads();
    }
    int carry = (tid == 0) ? 0 : psum[tid - 1];
#pragma unroll
    for (int j = 0; j < CB; ++j) {
        int idx = base + j;
        if (idx < NB) {
            int c = cnt[idx];
            cnt[idx] = carry;
            carry += c;
        }
    }
    __syncthreads();

    unsigned short* co = chunkoff + ((size_t)g * NCHK + blk) * NB;
    for (int i = tid; i < NB; i += 256) co[i] = (unsigned short)cnt[i];
}

// ---------------------------------------------------------------------------
// 1b) scatter, grid (NCHK, L): cursors = packed u16 pairs (init from
//     chunkoff); rank-scatter payload {cv, rl} into LDS; coalesced copy-out.
//     46.3KB LDS -> 3 blocks/CU.
// ---------------------------------------------------------------------------
__global__ __launch_bounds__(256) void scatter_kernel(
    const int* __restrict__ edge_rows,
    const int* __restrict__ edge_cols,
    const float* __restrict__ edge_vals,
    const unsigned short* __restrict__ chunkoff,
    unsigned* __restrict__ cvT,              // [L][E] chunk-local payload
    unsigned char* __restrict__ rlT)         // [L][E] chunk-local row key
{
    __shared__ unsigned cur[(NB + 1) / 2];   // 6.25 KB packed u16 cursors
    __shared__ unsigned lcv[CHUNK];          // 32 KB
    __shared__ unsigned char lrl[CHUNK];     // 8 KB
    const int blk = blockIdx.x, g = blockIdx.y, tid = threadIdx.x;

    const unsigned short* co = chunkoff + ((size_t)g * NCHK + blk) * NB;
    for (int i = tid; i < (NB + 1) / 2; i += 256) {
        unsigned lo = co[2 * i];
        unsigned hi = (2 * i + 1 < NB) ? co[2 * i + 1] : 0u;
        cur[i] = lo | (hi << 16);
    }
    __syncthreads();

    const size_t eoff = (size_t)g * E + (size_t)blk * CHUNK;
    const int* rows = edge_rows + eoff;
    const int* cols = edge_cols + eoff;
    const float* vals = edge_vals + eoff;

    for (int i = tid; i < CHUNK; i += 256) {
        int r = rows[i];
        int b = r >> BSH;
        unsigned old = atomicAdd(&cur[b >> 1], (b & 1) ? 0x10000u : 1u);
        int pos = (old >> ((b & 1) * 16)) & 0xFFFFu;
        lcv[pos] = (unsigned)cols[i] | (bf16rne(__float_as_uint(vals[i])) << 16);
        lrl[pos] = (unsigned char)(r & 15);
    }
    __syncthreads();

    unsigned* cw = cvT + eoff;
    unsigned char* rw = rlT + eoff;
    for (int i = tid; i < CHUNK; i += 256) cw[i] = lcv[i];
    for (int i = tid * 4; i < CHUNK; i += 1024)
        *reinterpret_cast<uint*>(rw + i) = *reinterpret_cast<const uint*>(lrl + i);
}

// ---------------------------------------------------------------------------
// 2a) Column pass: pcnt counts -> within-bucket cross-chunk offsets;
//     bucket totals -> bstart.
// ---------------------------------------------------------------------------
__global__ __launch_bounds__(256) void scan1_kernel(
    unsigned short* __restrict__ pcnt, int* __restrict__ bstart)
{
    const int b = blockIdx.x * 256 + threadIdx.x;
    const int g = blockIdx.y;
    if (b >= NB) return;
    unsigned run = 0;
    unsigned short* p = pcnt + (size_t)g * NCHK * NB + b;
    for (int blk = 0; blk < NCHK; ++blk) {
        unsigned v = p[(size_t)blk * NB];
        p[(size_t)blk * NB] = (unsigned short)run;
        run += v;
    }
    bstart[(size_t)g * (NB + 1) + b] = (int)run;
}

// ---------------------------------------------------------------------------
// 2b) Per-graph exclusive scan of bucket totals.
// ---------------------------------------------------------------------------
__global__ __launch_bounds__(1024) void scan2_kernel(int* __restrict__ bstart)
{
    __shared__ int sums[1024];
    int* bs = bstart + (size_t)blockIdx.x * (NB + 1);
    const int t = threadIdx.x;
    int tv[4];
    int s = 0;
#pragma unroll
    for (int i = 0; i < 4; ++i) {
        int idx = t * 4 + i;
        tv[i] = (idx < NB) ? bs[idx] : 0;
        s += tv[i];
    }
    sums[t] = s;
    __syncthreads();
    for (int off = 1; off < 1024; off <<= 1) {
        int v = (t >= off) ? sums[t - off] : 0;
        __syncthreads();
        sums[t] += v;
        __syncthreads();
    }
    int ex = (t == 0) ? 0 : sums[t - 1];
#pragma unroll
    for (int i = 0; i < 4; ++i) {
        int idx = t * 4 + i;
        if (idx < NB) { bs[idx] = ex; ex += tv[i]; }
    }
    if (t == 0) bs[NB] = E;
}

// ---------------------------------------------------------------------------
// 3) sort2 (pull payload), grid (NB, L): unchanged from R12.
// ---------------------------------------------------------------------------
__global__ __launch_bounds__(256) void sort2_kernel(
    const unsigned* __restrict__ cvT,            // [L][E]
    const unsigned char* __restrict__ rlT,       // [L][E]
    const unsigned short* __restrict__ pcnt,     // [L][NCHK][NB] offsets
    const unsigned short* __restrict__ chunkoff, // [L][NCHK][NB]
    const int* __restrict__ bstart,              // [L][NB+1]
    unsigned* __restrict__ cv,                   // [L][E] final
    int* __restrict__ rowptr)                    // [L][N+1]
{
    __shared__ unsigned su_cv[CAP], ss_cv[CAP];
    __shared__ unsigned char su_rl[CAP];
    __shared__ int rc[17], rcur[16];
    const int b = blockIdx.x, g = blockIdx.y, tid = threadIdx.x;
    const int beg = bstart[(size_t)g * (NB + 1) + b];
    const int tot = bstart[(size_t)g * (NB + 1) + b + 1] - beg;
    const int cnt = tot < CAP ? tot : CAP;
    int* rp = rowptr + (size_t)g * (N + 1);
    if (b == 0 && tid == 0) rp[N] = E;
    if (tid < 17) rc[tid] = 0;

    if (tid < NCHK) {
        const int c = tid;
        const size_t pbase = ((size_t)g * NCHK + c) * NB + b;
        int off = pcnt[pbase];
        int nxt = (c == NCHK - 1) ? tot : (int)pcnt[pbase + NB];
        int len = nxt - off;
        const size_t wbase = (size_t)g * E + (size_t)c * CHUNK + chunkoff[pbase];
        const unsigned* cw = cvT + wbase;
        const unsigned char* rw = rlT + wbase;
        for (int i = 0; i < len; ++i) {
            int p = off + i;
            if (p < CAP) { su_cv[p] = cw[i]; su_rl[p] = rw[i]; }
        }
    }
    __syncthreads();

    for (int i = tid; i < cnt; i += 256) atomicAdd(&rc[su_rl[i] + 1], 1);
    __syncthreads();
    if (tid == 0) {
        int run = 0;
#pragma unroll
        for (int r = 1; r <= 16; ++r) { run += rc[r]; rc[r] = run; }
    }
    __syncthreads();
    if (tid < 16) {
        rcur[tid] = rc[tid];
        rp[b * 16 + tid] = beg + rc[tid];
    }
    __syncthreads();
    for (int i = tid; i < cnt; i += 256) {
        int p = atomicAdd(&rcur[su_rl[i]], 1);
        ss_cv[p] = su_cv[i];
    }
    __syncthreads();
    unsigned* cvg = cv + (size_t)g * E;
    for (int i = tid; i < cnt; i += 256) cvg[beg + i] = ss_cv[i];
}

// ---------------------------------------------------------------------------
// 4) FUSED gather + MFMA projection, pass q, grid (N/16):
//    Block = 256 thr = 4 waves = 16 rows. Per graph l: wave w's 4 subs
//    gather rows w*4+{0..3} (R12 structure: 16-edge batches, branch-free
//    unrolled, 16 independent xq loads per sub) -> bf16 tile[16][16] in LDS
//    -> barrier -> each wave: A-frag from tile, 2 MFMAs (f strip 32w..32w+31)
//    accumulating over l in registers -> barrier. One out RMW per q.
// ---------------------------------------------------------------------------
__global__ __launch_bounds__(256) void fused_kernel(
    const unsigned* __restrict__ xb,      // [4][N][16]
    const unsigned* __restrict__ cv,      // [L][E]
    const int* __restrict__ rowptr,       // [L][N+1]
    const unsigned* __restrict__ WbT,     // [L][128][64] bf16 pairs (scaled)
    const float* __restrict__ bias,
    float* __restrict__ out,
    int q)
{
    __shared__ unsigned tile[16][16];     // 1 KB: [tile row][feature pair]

    const int tid = threadIdx.x;
    const int lane = tid & 63;
    const int wave = tid >> 6;
    const int sub = lane >> 4;
    const int fl = lane & 15;
    const int subbase = lane & 48;
    const int trow = wave * 4 + sub;                  // tile row this sub owns
    const int row = blockIdx.x * 16 + trow;
    const int lrow = lane & 15, kgrp = lane >> 4;

    const unsigned* xq = xb + (size_t)q * N * 16;

    f32x4 acc[2] = {};                                // f = wave*32 + t*16 + lrow

    for (int l = 0; l < L; ++l) {
        const unsigned* cvg = cv + (size_t)l * E;
        const int* rp = rowptr + (size_t)l * (N + 1);
        const int beg = rp[row], end = rp[row + 1];
        float accx = 0.f, accy = 0.f;

        for (int base = beg; base < end; base += 16) {
            const int cnt = end - base;
            unsigned cvr = (fl < cnt) ? cvg[base + fl] : 0u;
#pragma unroll
            for (int k = 0; k < 16; k += 4) {
                unsigned c0 = __shfl(cvr, subbase + k + 0);
                unsigned c1 = __shfl(cvr, subbase + k + 1);
                unsigned c2 = __shfl(cvr, subbase + k + 2);
                unsigned c3 = __shfl(cvr, subbase + k + 3);
                unsigned x0 = xq[(size_t)(c0 & 0xFFFFu) * 16 + fl];
                unsigned x1 = xq[(size_t)(c1 & 0xFFFFu) * 16 + fl];
                unsigned x2 = xq[(size_t)(c2 & 0xFFFFu) * 16 + fl];
                unsigned x3 = xq[(size_t)(c3 & 0xFFFFu) * 16 + fl];
                float v0 = __uint_as_float(c0 & 0xFFFF0000u);  // pad -> +0.0
                float v1 = __uint_as_float(c1 & 0xFFFF0000u);
                float v2 = __uint_as_float(c2 & 0xFFFF0000u);
                float v3 = __uint_as_float(c3 & 0xFFFF0000u);
                accx = fmaf(v0, __uint_as_float(x0 << 16), accx);
                accy = fmaf(v0, __uint_as_float(x0 & 0xFFFF0000u), accy);
                accx = fmaf(v1, __uint_as_float(x1 << 16), accx);
                accy = fmaf(v1, __uint_as_float(x1 & 0xFFFF0000u), accy);
                accx = fmaf(v2, __uint_as_float(x2 << 16), accx);
                accy = fmaf(v2, __uint_as_float(x2 & 0xFFFF0000u), accy);
                accx = fmaf(v3, __uint_as_float(x3 << 16), accx);
                accy = fmaf(v3, __uint_as_float(x3 & 0xFFFF0000u), accy);
            }
        }
        tile[trow][fl] = bf16rne(__float_as_uint(accx)) |
                         (bf16rne(__float_as_uint(accy)) << 16);
        __syncthreads();

        U4B8 a;
        a.u = *reinterpret_cast<const uint4*>(&tile[lrow][kgrp * 4]);
#pragma unroll
        for (int t = 0; t < 2; ++t) {
            const int f = wave * 32 + t * 16 + lrow;
            U4B8 bb;
            bb.u = *reinterpret_cast<const uint4*>(
                WbT + ((size_t)l * D + f) * 64 + q * 16 + kgrp * 4);
            acc[t] = __builtin_amdgcn_mfma_f32_16x16x32_bf16(a.b, bb.b, acc[t], 0, 0, 0);
        }
        __syncthreads();
    }

#pragma unroll
    for (int t = 0; t < 2; ++t) {
        const int f = wave * 32 + t * 16 + lrow;
#pragma unroll
        for (int i = 0; i < 4; ++i) {
            int orow = blockIdx.x * 16 + kgrp * 4 + i;
            float* p = out + (size_t)orow * D + f;
            float v = acc[t][i];
            *p = (q == 0) ? v + bias[f] : *p + v;
        }
    }
}

extern "C" void kernel_launch(void* const* d_in, const int* in_sizes, int n_in,
                              void* d_out, int out_size, void* d_ws, size_t ws_size,
                              hipStream_t stream)
{
    const float* x         = (const float*)d_in[0];
    const int*   edge_rows = (const int*)d_in[1];
    const int*   edge_cols = (const int*)d_in[2];
    const float* edge_vals = (const float*)d_in[3];
    const float* W         = (const float*)d_in[4];
    const float* mix       = (const float*)d_in[5];
    const float* bias      = (const float*)d_in[6];
    float* out = (float*)d_out;

    // Workspace (~47.6 MB), layout as R12 (y gone):
    // cvT [L][E] u32 (12.8M) | rlT [L][E] u8 (3.2M) | pcnt u16 (2.5M) |
    // chunkoff u16 (2.5M) | bstart (50K) | rowptr (0.8M) | cv [L][E] (12.8M) |
    // xb [4][N][16] (12.8M) | WbT (128K)
    unsigned*       cvT      = (unsigned*)d_ws;
    unsigned char*  rlT      = (unsigned char*)(cvT + (size_t)L * E);
    unsigned short* pcnt     = (unsigned short*)(rlT + (size_t)L * E);
    unsigned short* chunkoff = pcnt + (size_t)L * NCHK * NB;
    int*            bstart   = (int*)(chunkoff + (size_t)L * NCHK * NB);
    int*            rowptr   = bstart + (size_t)L * (NB + 1);
    unsigned*       cv       = (unsigned*)(rowptr + (size_t)L * (N + 1));
    unsigned*       xb       = cv + (size_t)L * E;
    unsigned*       WbT      = xb + (size_t)4 * N * 16;

    cvt_x_kernel<<<(N * 64) / 256, 256, 0, stream>>>(x, xb);
    cvt_w_kernel<<<(L * D * 64) / 256, 256, 0, stream>>>(W, mix, WbT);
    hist_kernel<<<dim3(NCHK, L), 256, 0, stream>>>(edge_rows, pcnt, chunkoff);
    scatter_kernel<<<dim3(NCHK, L), 256, 0, stream>>>(edge_rows, edge_cols,
                                                      edge_vals, chunkoff, cvT, rlT);
    scan1_kernel<<<dim3((NB + 255) / 256, L), 256, 0, stream>>>(pcnt, bstart);
    scan2_kernel<<<L, 1024, 0, stream>>>(bstart);
    sort2_kernel<<<dim3(NB, L), 256, 0, stream>>>(cvT, rlT, pcnt, chunkoff, bstart,
                                                  cv, rowptr);

    for (int q = 0; q < 4; ++q)
        fused_kernel<<<N / 16, 256, 0, stream>>>(xb, cv, rowptr, WbT, bias, out, q);
}